// Round 18
// baseline (160.602 us; speedup 1.0000x reference)
//
#include <hip/hip_runtime.h>

// Problem constants (from reference)
constexpr int B   = 4;
constexpr int CF  = 3;    // feat channels
constexpr int CM  = 21;   // mask channels
constexpr int H   = 128;
constexpr int W   = 128;
constexpr int KS  = 7;
constexpr int PAD = 3;
constexpr int CENTER = (KS * KS) / 2;  // 24
constexpr int NNB = KS * KS - 1;       // 48 neighbors
constexpr int NUM_ITER = 10;

constexpr int TILE = 16;
constexpr int TH   = TILE + 2 * PAD;   // 22 (aff-kernel halo tile)
constexpr int TS   = 24;
constexpr int HW   = H * W;

// fuse-2 geometry
constexpr int IN   = TILE + 4 * PAD;   // 28 input halo tile
constexpr int IND  = 15;               // input LDS row stride in DWORDS
constexpr int MD   = 22;               // intermediate (iter t) region
constexpr int MDD  = 12;               // mid LDS row stride in DWORDS
constexpr int CPB  = 7;                // channels per block (3 groups)
constexpr int INP  = CPB * IN * IND;   // dwords per input parity copy
constexpr int MDP  = CPB * MD * MDD;   // dwords per mid parity copy

// bf16 helpers (round-to-nearest-even; no NaN in this data)
__device__ __forceinline__ unsigned short f2b(float v) {
    unsigned int x = __float_as_uint(v);
    x += 0x7fffu + ((x >> 16) & 1u);
    return (unsigned short)(x >> 16);
}
__device__ __forceinline__ float blo(unsigned int d) { return __uint_as_float(d << 16); }
__device__ __forceinline__ float bhi(unsigned int d) { return __uint_as_float(d & 0xffff0000u); }

// ---------------------------------------------------------------------------
// Kernel 1: per-pixel 48-way softmax affinity (validated R4-R17, unchanged).
// PLANE-major layout (coalesced): aff[((b*48 + n)*H + h)*W + w]
// ---------------------------------------------------------------------------
__global__ __launch_bounds__(256) void aff_kernel(const float* __restrict__ feats,
                                                  float* __restrict__ aff) {
    __shared__ float tile[CF][TH][TS];
    const int tx = threadIdx.x, ty = threadIdx.y;
    const int bx = blockIdx.x * TILE, by = blockIdx.y * TILE;
    const int b  = blockIdx.z;
    const int tid = ty * TILE + tx;

    for (int c = 0; c < CF; ++c) {
        const float* src = feats + (size_t)(b * CF + c) * HW;
        for (int idx = tid; idx < TH * TH; idx += 256) {
            const int r  = idx / TH, cc = idx - r * TH;
            const int gh = min(max(by + r  - PAD, 0), H - 1);
            const int gw = min(max(bx + cc - PAD, 0), W - 1);
            tile[c][r][cc] = src[gh * W + gw];
        }
    }
    __syncthreads();

    float q[CF], inv[CF];
    #pragma unroll
    for (int c = 0; c < CF; ++c) {
        const float* tp = &tile[c][ty][tx];
        q[c] = tp[PAD * TS + PAD];
        float s = 0.f, s2 = 0.f;
        #pragma unroll
        for (int i = 0; i < KS; ++i)
            #pragma unroll
            for (int j = 0; j < KS; ++j) {
                if (i == PAD && j == PAD) continue;
                const float v = tp[i * TS + j];
                s += v; s2 += v * v;
            }
        const float mean = s * (1.0f / NNB);
        const float var  = fmaxf(s2 - (float)NNB * mean * mean, 0.f) * (1.0f / (NNB - 1));
        inv[c] = 1.0f / (1e-8f + 0.1f * sqrtf(var));
    }

    float a[NNB];
    float mx = -1e30f;
    #pragma unroll
    for (int i = 0; i < KS; ++i)
        #pragma unroll
        for (int j = 0; j < KS; ++j) {
            const int nn = i * KS + j;
            if (nn == CENTER) continue;
            const int n = (nn < CENTER) ? nn : nn - 1;
            float t = 0.f;
            #pragma unroll
            for (int c = 0; c < CF; ++c)
                t += fabsf(tile[c][ty + i][tx + j] - q[c]) * inv[c];
            a[n] = -t * (1.0f / CF);
            mx = fmaxf(mx, a[n]);
        }
    float ssum = 0.f;
    #pragma unroll
    for (int n = 0; n < NNB; ++n) { a[n] = __expf(a[n] - mx); ssum += a[n]; }
    const float rs = 1.0f / ssum;

    const int h = by + ty, w = bx + tx;
    #pragma unroll
    for (int n = 0; n < NNB; ++n)
        aff[(((size_t)b * NNB + n) * H + h) * W + w] = a[n] * rs;
}

// ---------------------------------------------------------------------------
// Kernel 2: TWO fused iterations, bf16 taps with DUAL-PARITY LDS copies.
// Copy 0: element e at u16 slot e. Copy 1: element e at u16 slot e-1.
// A thread with window start ac picks copy (ac&1) and reads 4 aligned dwords
// from k0=ac>>1 -> wv[j] = unpack[j], NO per-row parity selects.
// Sweep order: ring(228 border mid px) -> own(center 256 = output px, whose
// aff stays in a[48] for pass 2 -> no third aff load).
// ---------------------------------------------------------------------------
__global__ __launch_bounds__(256, 3) void fuse2_kernel(const float* __restrict__ mi,
                                                       const float* __restrict__ aff,
                                                       float* __restrict__ mo) {
    __shared__ unsigned int in_u[2 * INP];   // 23.0 KB (two parity copies)
    __shared__ unsigned int md_u[2 * MDP];   // 14.4 KB

    const int tx = threadIdx.x, ty = threadIdx.y;
    const int tid = ty * TILE + tx;
    const int bx = blockIdx.x * TILE, by = blockIdx.y * TILE;
    const int zz = blockIdx.z;
    const int b  = zz / 3, g = zz % 3;
    const int c0 = g * CPB;

    const float* ab = aff + (size_t)b * NNB * HW;

    // ---- ring geometry (border of 22x22 mid region), clamped & unconditional
    const int t2 = min(tid, 227);
    int rr_, qq_;
    if (t2 < 66)       { rr_ = t2 / MD;                    qq_ = t2 - rr_ * MD; }
    else if (t2 < 132) { const int s = t2 - 66;  rr_ = 19 + s / MD; qq_ = s % MD; }
    else               { const int s = t2 - 132; rr_ = 3 + s / 6;
                         const int u = s % 6;    qq_ = (u < 3) ? u : 16 + u; }
    const int gh_r = min(max(by - PAD + rr_, 0), H - 1);
    const int gw_r = min(max(bx - PAD + qq_, 0), W - 1);

    // a[48] := ring-pixel aff
    float a[NNB];
    {
        const float* ap = ab + (size_t)gh_r * W + gw_r;
        #pragma unroll
        for (int n = 0; n < NNB; ++n) a[n] = ap[(size_t)n * HW];
    }

    // ---- stage 28x28 x 7ch input halo as bf16 into BOTH parity copies
    {
        const float* src = mi + (size_t)(b * CM + c0) * HW;
        for (int s = tid; s < IN * IN; s += 256) {
            const int rr = s / IN, qq = s - rr * IN;
            const int ih = min(max(by - 2 * PAD + rr, 0), H - 1);
            const int iw = min(max(bx - 2 * PAD + qq, 0), W - 1);
            const int go = ih * W + iw;
            #pragma unroll
            for (int c = 0; c < CPB; ++c) {
                const unsigned short v = f2b(src[c * HW + go]);
                unsigned short* rowA = (unsigned short*)&in_u[(c * IN + rr) * IND];
                unsigned short* rowB = (unsigned short*)&in_u[INP + (c * IN + rr) * IND];
                rowA[qq] = v;
                if (qq >= 1) rowB[qq - 1] = v;
            }
        }
    }
    __syncthreads();

    // ==== sweep 1: iteration t at RING mid pixels (store predicated) ====
    {
        const int ar = gh_r - by + PAD;               // window top row in in_u
        const int ac = gw_r - bx + PAD;               // window left col [0..21]
        const int psel = (ac & 1) ? INP : 0;
        const int k0 = ac >> 1;
        const bool wr = (tid < 228);
        #pragma unroll
        for (int c = 0; c < CPB; ++c) {
            float s = 0.f;
            #pragma unroll
            for (int i = 0; i < KS; ++i) {
                const unsigned int* rp = &in_u[psel + (c * IN + ar + i) * IND + k0];
                const unsigned int d0 = rp[0], d1 = rp[1], d2 = rp[2], d3 = rp[3];
                const float wv[7] = { blo(d0), bhi(d0), blo(d1), bhi(d1),
                                      blo(d2), bhi(d2), blo(d3) };
                #pragma unroll
                for (int j = 0; j < KS; ++j) {
                    const int nn = i * KS + j;
                    if (nn == CENTER) continue;
                    const int n = (nn < CENTER) ? nn : nn - 1;
                    s += a[n] * wv[j];
                }
            }
            if (wr) {
                const unsigned short v = f2b(s);
                ((unsigned short*)&md_u[(c * MD + rr_) * MDD])[qq_] = v;
                if (qq_ >= 1)
                    ((unsigned short*)&md_u[MDP + (c * MD + rr_) * MDD])[qq_ - 1] = v;
            }
        }
    }

    // ==== sweep 2: iteration t at OWN pixel; a[48] := own aff (kept for pass 2)
    {
        const float* ap = ab + (size_t)(by + ty) * W + (bx + tx);
        #pragma unroll
        for (int n = 0; n < NNB; ++n) a[n] = ap[(size_t)n * HW];
    }
    {
        const int ar = ty + PAD, ac = tx + PAD;       // interior, unclamped
        const int psel = (ac & 1) ? INP : 0;
        const int k0 = ac >> 1;
        const int mq = tx + PAD;                      // mid col (>=3 -> B always)
        #pragma unroll
        for (int c = 0; c < CPB; ++c) {
            float s = 0.f;
            #pragma unroll
            for (int i = 0; i < KS; ++i) {
                const unsigned int* rp = &in_u[psel + (c * IN + ar + i) * IND + k0];
                const unsigned int d0 = rp[0], d1 = rp[1], d2 = rp[2], d3 = rp[3];
                const float wv[7] = { blo(d0), bhi(d0), blo(d1), bhi(d1),
                                      blo(d2), bhi(d2), blo(d3) };
                #pragma unroll
                for (int j = 0; j < KS; ++j) {
                    const int nn = i * KS + j;
                    if (nn == CENTER) continue;
                    const int n = (nn < CENTER) ? nn : nn - 1;
                    s += a[n] * wv[j];
                }
            }
            const unsigned short v = f2b(s);
            ((unsigned short*)&md_u[(c * MD + ty + PAD) * MDD])[mq] = v;
            ((unsigned short*)&md_u[MDP + (c * MD + ty + PAD) * MDD])[mq - 1] = v;
        }
    }
    __syncthreads();

    // ==== pass 2: iteration t+1 at own output pixel (a[48] already = own aff)
    {
        const int psel = (tx & 1) ? MDP : 0;
        const int k0 = tx >> 1;
        float* dp = mo + (size_t)(b * CM + c0) * HW + (size_t)(by + ty) * W + (bx + tx);
        #pragma unroll
        for (int c = 0; c < CPB; ++c) {
            float s = 0.f;
            #pragma unroll
            for (int i = 0; i < KS; ++i) {
                const unsigned int* rp = &md_u[psel + (c * MD + ty + i) * MDD + k0];
                const unsigned int d0 = rp[0], d1 = rp[1], d2 = rp[2], d3 = rp[3];
                const float wv[7] = { blo(d0), bhi(d0), blo(d1), bhi(d1),
                                      blo(d2), bhi(d2), blo(d3) };
                #pragma unroll
                for (int j = 0; j < KS; ++j) {
                    const int nn = i * KS + j;
                    if (nn == CENTER) continue;
                    const int n = (nn < CENTER) ? nn : nn - 1;
                    s += a[n] * wv[j];
                }
            }
            dp[(size_t)c * HW] = s;
        }
    }
}

// ---------------------------------------------------------------------------
extern "C" void kernel_launch(void* const* d_in, const int* in_sizes, int n_in,
                              void* d_out, int out_size, void* d_ws, size_t ws_size,
                              hipStream_t stream) {
    const float* feats = (const float*)d_in[0];
    const float* mask  = (const float*)d_in[1];
    float* out = (float*)d_out;

    float* aff  = (float*)d_ws;                               // 12.58 MB (plane-major)
    float* buf0 = aff  + (size_t)B * NNB * HW;                // 5.5 MB
    float* buf1 = buf0 + (size_t)B * CM  * HW;                // 5.5 MB

    aff_kernel<<<dim3(W / TILE, H / TILE, B), dim3(TILE, TILE), 0, stream>>>(feats, aff);

    // 5 fused kernels = 10 iterations; last lands in d_out
    dim3 grid(W / TILE, H / TILE, B * 3);
    dim3 blk(TILE, TILE);
    fuse2_kernel<<<grid, blk, 0, stream>>>(mask, aff, buf0);
    fuse2_kernel<<<grid, blk, 0, stream>>>(buf0, aff, buf1);
    fuse2_kernel<<<grid, blk, 0, stream>>>(buf1, aff, buf0);
    fuse2_kernel<<<grid, blk, 0, stream>>>(buf0, aff, buf1);
    fuse2_kernel<<<grid, blk, 0, stream>>>(buf1, aff, out);
}

// Round 19
// 132.655 us; speedup vs baseline: 1.2107x; 1.2107x over previous
//
#include <hip/hip_runtime.h>

// Problem constants (from reference)
constexpr int B   = 4;
constexpr int CF  = 3;    // feat channels
constexpr int CM  = 21;   // mask channels
constexpr int H   = 128;
constexpr int W   = 128;
constexpr int KS  = 7;
constexpr int PAD = 3;
constexpr int CENTER = (KS * KS) / 2;  // 24
constexpr int NNB = KS * KS - 1;       // 48 neighbors
constexpr int NUM_ITER = 10;

constexpr int TILE = 16;
constexpr int TH   = TILE + 2 * PAD;   // 22 (aff-kernel halo tile)
constexpr int TS   = 24;
constexpr int HW   = H * W;

// fuse-2 geometry
constexpr int IN   = TILE + 4 * PAD;   // 28 input halo tile
constexpr int IND  = 15;               // input LDS row stride in DWORDS (30 f16)
constexpr int MD   = 22;               // intermediate (iter t) region
constexpr int MDD  = 12;               // mid LDS row stride in DWORDS (24 f16)
constexpr int CPB  = 7;                // channels per block (3 groups)

typedef _Float16 h2 __attribute__((ext_vector_type(2)));

__device__ __forceinline__ unsigned short f2h(float v) {
    _Float16 h = (_Float16)v;
    return __builtin_bit_cast(unsigned short, h);
}
__device__ __forceinline__ float hlo(unsigned int d) {
    h2 p = __builtin_bit_cast(h2, d); return (float)p.x;
}
__device__ __forceinline__ float hhi(unsigned int d) {
    h2 p = __builtin_bit_cast(h2, d); return (float)p.y;
}

// weight of (row i, col j) from a[48] with the center zeroed (compile-time i,j)
#define WIJ(i, j) ((((i) * KS + (j)) == CENTER) ? 0.f : \
    a[(((i) * KS + (j)) < CENTER) ? ((i) * KS + (j)) : ((i) * KS + (j) - 1)])

// ---------------------------------------------------------------------------
// Kernel 1: per-pixel 48-way softmax affinity (validated R4-R18, unchanged).
// PLANE-major layout (coalesced): aff[((b*48 + n)*H + h)*W + w]
// ---------------------------------------------------------------------------
__global__ __launch_bounds__(256) void aff_kernel(const float* __restrict__ feats,
                                                  float* __restrict__ aff) {
    __shared__ float tile[CF][TH][TS];
    const int tx = threadIdx.x, ty = threadIdx.y;
    const int bx = blockIdx.x * TILE, by = blockIdx.y * TILE;
    const int b  = blockIdx.z;
    const int tid = ty * TILE + tx;

    for (int c = 0; c < CF; ++c) {
        const float* src = feats + (size_t)(b * CF + c) * HW;
        for (int idx = tid; idx < TH * TH; idx += 256) {
            const int r  = idx / TH, cc = idx - r * TH;
            const int gh = min(max(by + r  - PAD, 0), H - 1);
            const int gw = min(max(bx + cc - PAD, 0), W - 1);
            tile[c][r][cc] = src[gh * W + gw];
        }
    }
    __syncthreads();

    float q[CF], inv[CF];
    #pragma unroll
    for (int c = 0; c < CF; ++c) {
        const float* tp = &tile[c][ty][tx];
        q[c] = tp[PAD * TS + PAD];
        float s = 0.f, s2 = 0.f;
        #pragma unroll
        for (int i = 0; i < KS; ++i)
            #pragma unroll
            for (int j = 0; j < KS; ++j) {
                if (i == PAD && j == PAD) continue;
                const float v = tp[i * TS + j];
                s += v; s2 += v * v;
            }
        const float mean = s * (1.0f / NNB);
        const float var  = fmaxf(s2 - (float)NNB * mean * mean, 0.f) * (1.0f / (NNB - 1));
        inv[c] = 1.0f / (1e-8f + 0.1f * sqrtf(var));
    }

    float a[NNB];
    float mx = -1e30f;
    #pragma unroll
    for (int i = 0; i < KS; ++i)
        #pragma unroll
        for (int j = 0; j < KS; ++j) {
            const int nn = i * KS + j;
            if (nn == CENTER) continue;
            const int n = (nn < CENTER) ? nn : nn - 1;
            float t = 0.f;
            #pragma unroll
            for (int c = 0; c < CF; ++c)
                t += fabsf(tile[c][ty + i][tx + j] - q[c]) * inv[c];
            a[n] = -t * (1.0f / CF);
            mx = fmaxf(mx, a[n]);
        }
    float ssum = 0.f;
    #pragma unroll
    for (int n = 0; n < NNB; ++n) { a[n] = __expf(a[n] - mx); ssum += a[n]; }
    const float rs = 1.0f / ssum;

    const int h = by + ty, w = bx + tx;
    #pragma unroll
    for (int n = 0; n < NNB; ++n)
        aff[(((size_t)b * NNB + n) * H + h) * W + w] = a[n] * rs;
}

// ---------------------------------------------------------------------------
// Kernel 2: TWO fused iterations. f16 single-copy LDS; parity folded into
// PRE-SHIFTED zero-padded weights (built once per sweep); inner row =
// 4 aligned dwords + 4 v_dot2_f32_f16 (or unpack+FMA fallback).
// Sweeps: ring(228, ring aff) -> center(own aff, kept) -> pass2(reuses own).
// ---------------------------------------------------------------------------
__global__ __launch_bounds__(256, 3) void fuse2_kernel(const float* __restrict__ mi,
                                                       const float* __restrict__ aff,
                                                       float* __restrict__ mo) {
    __shared__ unsigned int in_u[CPB][IN][IND];   // f16: 11.5 KB
    __shared__ unsigned int md_u[CPB][MD][MDD];   // f16:  7.4 KB

    const int tx = threadIdx.x, ty = threadIdx.y;
    const int tid = ty * TILE + tx;
    const int bx = blockIdx.x * TILE, by = blockIdx.y * TILE;
    const int zz = blockIdx.z;
    const int b  = zz / 3, g = zz % 3;
    const int c0 = g * CPB;

    const float* ab = aff + (size_t)b * NNB * HW;

#if __has_builtin(__builtin_amdgcn_fdot2)
    h2 hw[KS][4];
    #define BUILD_W(par)                                                     \
        _Pragma("unroll")                                                    \
        for (int i = 0; i < KS; ++i) {                                       \
            float awk[8];                                                    \
            _Pragma("unroll")                                                \
            for (int k = 0; k < 8; ++k) {                                    \
                const float w0 = (k < 7)  ? WIJ(i, k)     : 0.f;             \
                const float w1 = (k >= 1) ? WIJ(i, k - 1) : 0.f;             \
                awk[k] = (par) ? w1 : w0;                                    \
            }                                                                \
            _Pragma("unroll")                                                \
            for (int m = 0; m < 4; ++m) {                                    \
                h2 t; t.x = (_Float16)awk[2 * m]; t.y = (_Float16)awk[2 * m + 1]; \
                hw[i][m] = t;                                                \
            }                                                                \
        }
    #define ROW_DOT(s, rp, i)                                                \
        do {                                                                 \
            const unsigned int d0 = (rp)[0], d1 = (rp)[1],                   \
                               d2 = (rp)[2], d3 = (rp)[3];                   \
            s = __builtin_amdgcn_fdot2(hw[i][0], __builtin_bit_cast(h2, d0), s, false); \
            s = __builtin_amdgcn_fdot2(hw[i][1], __builtin_bit_cast(h2, d1), s, false); \
            s = __builtin_amdgcn_fdot2(hw[i][2], __builtin_bit_cast(h2, d2), s, false); \
            s = __builtin_amdgcn_fdot2(hw[i][3], __builtin_bit_cast(h2, d3), s, false); \
        } while (0)
#else
    float fw[KS][8];
    #define BUILD_W(par)                                                     \
        _Pragma("unroll")                                                    \
        for (int i = 0; i < KS; ++i)                                         \
            _Pragma("unroll")                                                \
            for (int k = 0; k < 8; ++k) {                                    \
                const float w0 = (k < 7)  ? WIJ(i, k)     : 0.f;             \
                const float w1 = (k >= 1) ? WIJ(i, k - 1) : 0.f;             \
                fw[i][k] = (par) ? w1 : w0;                                  \
            }
    #define ROW_DOT(s, rp, i)                                                \
        do {                                                                 \
            const unsigned int d0 = (rp)[0], d1 = (rp)[1],                   \
                               d2 = (rp)[2], d3 = (rp)[3];                   \
            s += fw[i][0] * hlo(d0) + fw[i][1] * hhi(d0)                     \
               + fw[i][2] * hlo(d1) + fw[i][3] * hhi(d1)                     \
               + fw[i][4] * hlo(d2) + fw[i][5] * hhi(d2)                     \
               + fw[i][6] * hlo(d3) + fw[i][7] * hhi(d3);                    \
        } while (0)
#endif

    // ---- ring geometry (border of 22x22 mid region; R18-validated mapping)
    const int t2 = min(tid, 227);
    int rr_, qq_;
    if (t2 < 66)       { rr_ = t2 / MD;                    qq_ = t2 - rr_ * MD; }
    else if (t2 < 132) { const int s = t2 - 66;  rr_ = 19 + s / MD; qq_ = s % MD; }
    else               { const int s = t2 - 132; rr_ = 3 + s / 6;
                         const int u = s % 6;    qq_ = (u < 3) ? u : 16 + u; }
    const int gh_r = min(max(by - PAD + rr_, 0), H - 1);
    const int gw_r = min(max(bx - PAD + qq_, 0), W - 1);

    // a[48] := ring-pixel aff (unconditional; spill-safe)
    float a[NNB];
    {
        const float* ap = ab + (size_t)gh_r * W + gw_r;
        #pragma unroll
        for (int n = 0; n < NNB; ++n) a[n] = ap[(size_t)n * HW];
    }

    // ---- stage 28x28 x 7ch input halo as f16 (edge-clamped)
    {
        const float* src = mi + (size_t)(b * CM + c0) * HW;
        for (int s = tid; s < IN * IN; s += 256) {
            const int rr = s / IN, qq = s - rr * IN;
            const int ih = min(max(by - 2 * PAD + rr, 0), H - 1);
            const int iw = min(max(bx - 2 * PAD + qq, 0), W - 1);
            const int go = ih * W + iw;
            #pragma unroll
            for (int c = 0; c < CPB; ++c)
                ((unsigned short*)&in_u[c][rr][0])[qq] = f2h(src[c * HW + go]);
        }
    }
    __syncthreads();

    // ==== sweep 1: iteration t at RING mid pixels (store predicated) ====
    {
        const int ar = gh_r - by + PAD;               // window top row in in_u
        const int ac = gw_r - bx + PAD;               // window left col [0..21]
        const int k0 = ac >> 1;
        const int par = ac & 1;
        BUILD_W(par);
        const bool wr = (tid < 228);
        #pragma unroll
        for (int c = 0; c < CPB; ++c) {
            float s = 0.f;
            #pragma unroll
            for (int i = 0; i < KS; ++i) {
                const unsigned int* rp = &in_u[c][ar + i][k0];
                ROW_DOT(s, rp, i);
            }
            if (wr) ((unsigned short*)&md_u[c][rr_][0])[qq_] = f2h(s);
        }
    }

    // ==== sweep 2: iteration t at OWN pixel; a[48] := own aff (kept) ====
    {
        const float* ap = ab + (size_t)(by + ty) * W + (bx + tx);
        #pragma unroll
        for (int n = 0; n < NNB; ++n) a[n] = ap[(size_t)n * HW];
    }
    {
        const int ar = ty + PAD, ac = tx + PAD;       // interior, unclamped
        const int k0 = ac >> 1;
        const int par = ac & 1;
        BUILD_W(par);
        #pragma unroll
        for (int c = 0; c < CPB; ++c) {
            float s = 0.f;
            #pragma unroll
            for (int i = 0; i < KS; ++i) {
                const unsigned int* rp = &in_u[c][ar + i][k0];
                ROW_DOT(s, rp, i);
            }
            ((unsigned short*)&md_u[c][ty + PAD][0])[tx + PAD] = f2h(s);
        }
    }
    __syncthreads();

    // ==== pass 2: iteration t+1 at own output pixel (a[48] already own) ====
    {
        const int k0 = tx >> 1;
        const int par = tx & 1;
        BUILD_W(par);
        float* dp = mo + (size_t)(b * CM + c0) * HW + (size_t)(by + ty) * W + (bx + tx);
        #pragma unroll
        for (int c = 0; c < CPB; ++c) {
            float s = 0.f;
            #pragma unroll
            for (int i = 0; i < KS; ++i) {
                const unsigned int* rp = &md_u[c][ty + i][k0];
                ROW_DOT(s, rp, i);
            }
            dp[(size_t)c * HW] = s;
        }
    }
}

// ---------------------------------------------------------------------------
extern "C" void kernel_launch(void* const* d_in, const int* in_sizes, int n_in,
                              void* d_out, int out_size, void* d_ws, size_t ws_size,
                              hipStream_t stream) {
    const float* feats = (const float*)d_in[0];
    const float* mask  = (const float*)d_in[1];
    float* out = (float*)d_out;

    float* aff  = (float*)d_ws;                               // 12.58 MB (plane-major)
    float* buf0 = aff  + (size_t)B * NNB * HW;                // 5.5 MB
    float* buf1 = buf0 + (size_t)B * CM  * HW;                // 5.5 MB

    aff_kernel<<<dim3(W / TILE, H / TILE, B), dim3(TILE, TILE), 0, stream>>>(feats, aff);

    // 5 fused kernels = 10 iterations; last lands in d_out
    dim3 grid(W / TILE, H / TILE, B * 3);
    dim3 blk(TILE, TILE);
    fuse2_kernel<<<grid, blk, 0, stream>>>(mask, aff, buf0);
    fuse2_kernel<<<grid, blk, 0, stream>>>(buf0, aff, buf1);
    fuse2_kernel<<<grid, blk, 0, stream>>>(buf1, aff, buf0);
    fuse2_kernel<<<grid, blk, 0, stream>>>(buf0, aff, buf1);
    fuse2_kernel<<<grid, blk, 0, stream>>>(buf1, aff, out);
}

// Round 20
// 130.189 us; speedup vs baseline: 1.2336x; 1.0189x over previous
//
#include <hip/hip_runtime.h>

// Problem constants (from reference)
constexpr int B   = 4;
constexpr int CF  = 3;    // feat channels
constexpr int CM  = 21;   // mask channels
constexpr int H   = 128;
constexpr int W   = 128;
constexpr int KS  = 7;
constexpr int PAD = 3;
constexpr int CENTER = (KS * KS) / 2;  // 24
constexpr int NNB = KS * KS - 1;       // 48 neighbors
constexpr int NUM_ITER = 10;

constexpr int TILE = 16;
constexpr int TH   = TILE + 2 * PAD;   // 22 (aff-kernel halo tile)
constexpr int TS   = 24;
constexpr int HW   = H * W;

// fuse-2 geometry
constexpr int IN   = TILE + 4 * PAD;   // 28 input halo tile
constexpr int IND  = 15;               // input LDS row stride in DWORDS (30 f16)
constexpr int MD   = 22;               // intermediate (iter t) region
constexpr int MDD  = 12;               // mid LDS row stride in DWORDS (24 f16)
constexpr int CPB  = 7;                // channels per block (3 groups)

typedef _Float16 h2 __attribute__((ext_vector_type(2)));

__device__ __forceinline__ unsigned short f2h(float v) {
    _Float16 h = (_Float16)v;
    return __builtin_bit_cast(unsigned short, h);
}
__device__ __forceinline__ float hlo(unsigned int d) {
    h2 p = __builtin_bit_cast(h2, d); return (float)p.x;
}
__device__ __forceinline__ float hhi(unsigned int d) {
    h2 p = __builtin_bit_cast(h2, d); return (float)p.y;
}

// weight of (row i, col j) from f16 a[48] with the center zeroed
#define WIJ(i, j) ((((i) * KS + (j)) == CENTER) ? (_Float16)0.f : \
    a[(((i) * KS + (j)) < CENTER) ? ((i) * KS + (j)) : ((i) * KS + (j) - 1)])

// ---------------------------------------------------------------------------
// Kernel 1: per-pixel 48-way softmax affinity (validated math, f32 internal).
// NEW: stores aff as f16 (plane-major u16): aff[((b*48+n)*H + h)*W + w].
// Zero added error: fuse2's fdot2 path already quantized weights to f16.
// ---------------------------------------------------------------------------
__global__ __launch_bounds__(256) void aff_kernel(const float* __restrict__ feats,
                                                  unsigned short* __restrict__ aff) {
    __shared__ float tile[CF][TH][TS];
    const int tx = threadIdx.x, ty = threadIdx.y;
    const int bx = blockIdx.x * TILE, by = blockIdx.y * TILE;
    const int b  = blockIdx.z;
    const int tid = ty * TILE + tx;

    for (int c = 0; c < CF; ++c) {
        const float* src = feats + (size_t)(b * CF + c) * HW;
        for (int idx = tid; idx < TH * TH; idx += 256) {
            const int r  = idx / TH, cc = idx - r * TH;
            const int gh = min(max(by + r  - PAD, 0), H - 1);
            const int gw = min(max(bx + cc - PAD, 0), W - 1);
            tile[c][r][cc] = src[gh * W + gw];
        }
    }
    __syncthreads();

    float q[CF], inv[CF];
    #pragma unroll
    for (int c = 0; c < CF; ++c) {
        const float* tp = &tile[c][ty][tx];
        q[c] = tp[PAD * TS + PAD];
        float s = 0.f, s2 = 0.f;
        #pragma unroll
        for (int i = 0; i < KS; ++i)
            #pragma unroll
            for (int j = 0; j < KS; ++j) {
                if (i == PAD && j == PAD) continue;
                const float v = tp[i * TS + j];
                s += v; s2 += v * v;
            }
        const float mean = s * (1.0f / NNB);
        const float var  = fmaxf(s2 - (float)NNB * mean * mean, 0.f) * (1.0f / (NNB - 1));
        inv[c] = 1.0f / (1e-8f + 0.1f * sqrtf(var));
    }

    float a[NNB];
    float mx = -1e30f;
    #pragma unroll
    for (int i = 0; i < KS; ++i)
        #pragma unroll
        for (int j = 0; j < KS; ++j) {
            const int nn = i * KS + j;
            if (nn == CENTER) continue;
            const int n = (nn < CENTER) ? nn : nn - 1;
            float t = 0.f;
            #pragma unroll
            for (int c = 0; c < CF; ++c)
                t += fabsf(tile[c][ty + i][tx + j] - q[c]) * inv[c];
            a[n] = -t * (1.0f / CF);
            mx = fmaxf(mx, a[n]);
        }
    float ssum = 0.f;
    #pragma unroll
    for (int n = 0; n < NNB; ++n) { a[n] = __expf(a[n] - mx); ssum += a[n]; }
    const float rs = 1.0f / ssum;

    const int h = by + ty, w = bx + tx;
    #pragma unroll
    for (int n = 0; n < NNB; ++n)
        aff[(((size_t)b * NNB + n) * H + h) * W + w] = f2h(a[n] * rs);
}

// ---------------------------------------------------------------------------
// Kernel 2: TWO fused iterations (R19 structure). f16 LDS; f16 aff loads;
// parity folded into pre-shifted zero-padded f16 weights (no cvts in BUILD_W);
// inner row = 4 aligned dwords + 4 v_dot2_f32_f16.
// Sweeps: ring(228, ring aff) -> center(own aff, kept) -> pass2(reuses own).
// ---------------------------------------------------------------------------
__global__ __launch_bounds__(256, 3) void fuse2_kernel(const float* __restrict__ mi,
                                                       const unsigned short* __restrict__ aff,
                                                       float* __restrict__ mo) {
    __shared__ unsigned int in_u[CPB][IN][IND];   // f16: 11.5 KB
    __shared__ unsigned int md_u[CPB][MD][MDD];   // f16:  7.4 KB

    const int tx = threadIdx.x, ty = threadIdx.y;
    const int tid = ty * TILE + tx;
    const int bx = blockIdx.x * TILE, by = blockIdx.y * TILE;
    const int zz = blockIdx.z;
    const int b  = zz / 3, g = zz % 3;
    const int c0 = g * CPB;

    const unsigned short* ab = aff + (size_t)b * NNB * HW;

#if __has_builtin(__builtin_amdgcn_fdot2)
    h2 hw[KS][4];
    #define BUILD_W(par)                                                     \
        _Pragma("unroll")                                                    \
        for (int i = 0; i < KS; ++i) {                                       \
            _Float16 awk[8];                                                 \
            _Pragma("unroll")                                                \
            for (int k = 0; k < 8; ++k) {                                    \
                const _Float16 w0 = (k < 7)  ? WIJ(i, k)     : (_Float16)0.f; \
                const _Float16 w1 = (k >= 1) ? WIJ(i, k - 1) : (_Float16)0.f; \
                awk[k] = (par) ? w1 : w0;                                    \
            }                                                                \
            _Pragma("unroll")                                                \
            for (int m = 0; m < 4; ++m) {                                    \
                h2 t; t.x = awk[2 * m]; t.y = awk[2 * m + 1];                \
                hw[i][m] = t;                                                \
            }                                                                \
        }
    #define ROW_DOT(s, rp, i)                                                \
        do {                                                                 \
            const unsigned int d0 = (rp)[0], d1 = (rp)[1],                   \
                               d2 = (rp)[2], d3 = (rp)[3];                   \
            s = __builtin_amdgcn_fdot2(hw[i][0], __builtin_bit_cast(h2, d0), s, false); \
            s = __builtin_amdgcn_fdot2(hw[i][1], __builtin_bit_cast(h2, d1), s, false); \
            s = __builtin_amdgcn_fdot2(hw[i][2], __builtin_bit_cast(h2, d2), s, false); \
            s = __builtin_amdgcn_fdot2(hw[i][3], __builtin_bit_cast(h2, d3), s, false); \
        } while (0)
#else
    float fw[KS][8];
    #define BUILD_W(par)                                                     \
        _Pragma("unroll")                                                    \
        for (int i = 0; i < KS; ++i)                                         \
            _Pragma("unroll")                                                \
            for (int k = 0; k < 8; ++k) {                                    \
                const _Float16 w0 = (k < 7)  ? WIJ(i, k)     : (_Float16)0.f; \
                const _Float16 w1 = (k >= 1) ? WIJ(i, k - 1) : (_Float16)0.f; \
                fw[i][k] = (float)((par) ? w1 : w0);                         \
            }
    #define ROW_DOT(s, rp, i)                                                \
        do {                                                                 \
            const unsigned int d0 = (rp)[0], d1 = (rp)[1],                   \
                               d2 = (rp)[2], d3 = (rp)[3];                   \
            s += fw[i][0] * hlo(d0) + fw[i][1] * hhi(d0)                     \
               + fw[i][2] * hlo(d1) + fw[i][3] * hhi(d1)                     \
               + fw[i][4] * hlo(d2) + fw[i][5] * hhi(d2)                     \
               + fw[i][6] * hlo(d3) + fw[i][7] * hhi(d3);                    \
        } while (0)
#endif

    // ---- ring geometry (border of 22x22 mid region; R18/R19-validated)
    const int t2 = min(tid, 227);
    int rr_, qq_;
    if (t2 < 66)       { rr_ = t2 / MD;                    qq_ = t2 - rr_ * MD; }
    else if (t2 < 132) { const int s = t2 - 66;  rr_ = 19 + s / MD; qq_ = s % MD; }
    else               { const int s = t2 - 132; rr_ = 3 + s / 6;
                         const int u = s % 6;    qq_ = (u < 3) ? u : 16 + u; }
    const int gh_r = min(max(by - PAD + rr_, 0), H - 1);
    const int gw_r = min(max(bx - PAD + qq_, 0), W - 1);

    // a[48] := ring-pixel aff (f16, unconditional; spill-safe)
    _Float16 a[NNB];
    {
        const unsigned short* ap = ab + (size_t)gh_r * W + gw_r;
        #pragma unroll
        for (int n = 0; n < NNB; ++n)
            a[n] = __builtin_bit_cast(_Float16, ap[(size_t)n * HW]);
    }

    // ---- stage 28x28 x 7ch input halo as f16 (edge-clamped)
    {
        const float* src = mi + (size_t)(b * CM + c0) * HW;
        for (int s = tid; s < IN * IN; s += 256) {
            const int rr = s / IN, qq = s - rr * IN;
            const int ih = min(max(by - 2 * PAD + rr, 0), H - 1);
            const int iw = min(max(bx - 2 * PAD + qq, 0), W - 1);
            const int go = ih * W + iw;
            #pragma unroll
            for (int c = 0; c < CPB; ++c)
                ((unsigned short*)&in_u[c][rr][0])[qq] = f2h(src[c * HW + go]);
        }
    }
    __syncthreads();

    // ==== sweep 1: iteration t at RING mid pixels (store predicated) ====
    {
        const int ar = gh_r - by + PAD;               // window top row in in_u
        const int ac = gw_r - bx + PAD;               // window left col [0..21]
        const int k0 = ac >> 1;
        const int par = ac & 1;
        BUILD_W(par);
        const bool wr = (tid < 228);
        #pragma unroll
        for (int c = 0; c < CPB; ++c) {
            float s = 0.f;
            #pragma unroll
            for (int i = 0; i < KS; ++i) {
                const unsigned int* rp = &in_u[c][ar + i][k0];
                ROW_DOT(s, rp, i);
            }
            if (wr) ((unsigned short*)&md_u[c][rr_][0])[qq_] = f2h(s);
        }
    }

    // ==== sweep 2: iteration t at OWN pixel; a[48] := own aff (kept) ====
    {
        const unsigned short* ap = ab + (size_t)(by + ty) * W + (bx + tx);
        #pragma unroll
        for (int n = 0; n < NNB; ++n)
            a[n] = __builtin_bit_cast(_Float16, ap[(size_t)n * HW]);
    }
    {
        const int ar = ty + PAD, ac = tx + PAD;       // interior, unclamped
        const int k0 = ac >> 1;
        const int par = ac & 1;
        BUILD_W(par);
        #pragma unroll
        for (int c = 0; c < CPB; ++c) {
            float s = 0.f;
            #pragma unroll
            for (int i = 0; i < KS; ++i) {
                const unsigned int* rp = &in_u[c][ar + i][k0];
                ROW_DOT(s, rp, i);
            }
            ((unsigned short*)&md_u[c][ty + PAD][0])[tx + PAD] = f2h(s);
        }
    }
    __syncthreads();

    // ==== pass 2: iteration t+1 at own output pixel (a[48] already own) ====
    {
        const int k0 = tx >> 1;
        const int par = tx & 1;
        BUILD_W(par);
        float* dp = mo + (size_t)(b * CM + c0) * HW + (size_t)(by + ty) * W + (bx + tx);
        #pragma unroll
        for (int c = 0; c < CPB; ++c) {
            float s = 0.f;
            #pragma unroll
            for (int i = 0; i < KS; ++i) {
                const unsigned int* rp = &md_u[c][ty + i][k0];
                ROW_DOT(s, rp, i);
            }
            dp[(size_t)c * HW] = s;
        }
    }
}

// ---------------------------------------------------------------------------
extern "C" void kernel_launch(void* const* d_in, const int* in_sizes, int n_in,
                              void* d_out, int out_size, void* d_ws, size_t ws_size,
                              hipStream_t stream) {
    const float* feats = (const float*)d_in[0];
    const float* mask  = (const float*)d_in[1];
    float* out = (float*)d_out;

    unsigned short* aff = (unsigned short*)d_ws;              // 6.29 MB (f16 plane-major)
    float* buf0 = (float*)(aff + (size_t)B * NNB * HW);       // 5.5 MB
    float* buf1 = buf0 + (size_t)B * CM * HW;                 // 5.5 MB

    aff_kernel<<<dim3(W / TILE, H / TILE, B), dim3(TILE, TILE), 0, stream>>>(feats, aff);

    // 5 fused kernels = 10 iterations; last lands in d_out
    dim3 grid(W / TILE, H / TILE, B * 3);
    dim3 blk(TILE, TILE);
    fuse2_kernel<<<grid, blk, 0, stream>>>(mask, aff, buf0);
    fuse2_kernel<<<grid, blk, 0, stream>>>(buf0, aff, buf1);
    fuse2_kernel<<<grid, blk, 0, stream>>>(buf1, aff, buf0);
    fuse2_kernel<<<grid, blk, 0, stream>>>(buf0, aff, buf1);
    fuse2_kernel<<<grid, blk, 0, stream>>>(buf1, aff, out);
}